// Round 7
// baseline (549.341 us; speedup 1.0000x reference)
//
#include <hip/hip_runtime.h>
#include <math.h>

#define BLK 256
#define CH 8192          // edges per k_bin block
#define NBMAX 1024       // max buckets (256 nodes each)

// ================= binned + CSR path =================

// zero ghist + zacc; rowptr[n] = E
__global__ void k_init0(int* __restrict__ ghist, float* __restrict__ zacc,
                        int* __restrict__ rowptr, int nb, int ng, int n, int E,
                        int primary) {
  int i = blockIdx.x * BLK + threadIdx.x;
  if (i < nb) ghist[i] = 0;
  if (i < ng) zacc[i] = 0.f;
  if (primary && i == 0) rowptr[n] = E;
}

// per-bucket histogram of dst>>8
__global__ void k_hist(const int* __restrict__ dst, int* __restrict__ ghist,
                       int E, int nb, int chunk) {
  __shared__ int h[NBMAX];
  for (int i = threadIdx.x; i < NBMAX; i += BLK) h[i] = 0;
  __syncthreads();
  long long s0 = (long long)blockIdx.x * chunk;
  int c = (int)min((long long)chunk, (long long)E - s0);
  for (int i = threadIdx.x; i < c; i += BLK)
    atomicAdd(&h[dst[s0 + i] >> 8], 1);
  __syncthreads();
  for (int b = threadIdx.x; b < nb; b += BLK)
    if (h[b]) atomicAdd(&ghist[b], h[b]);
}

// exclusive scan of ghist -> base[0..nb], cursor=base
__global__ void k_scan(const int* __restrict__ ghist, int* __restrict__ base,
                       int* __restrict__ cursor, int nb, int E) {
  __shared__ int temp[BLK];
  int t = threadIdx.x;
  int v[4]; int sm = 0;
  #pragma unroll
  for (int k = 0; k < 4; ++k) {
    int idx = t * 4 + k;
    v[k] = (idx < nb) ? ghist[idx] : 0;
    sm += v[k];
  }
  temp[t] = sm; __syncthreads();
  int inc = sm;
  for (int off = 1; off < BLK; off <<= 1) {
    int u = (t >= off) ? temp[t - off] : 0; __syncthreads();
    inc += u; temp[t] = inc; __syncthreads();
  }
  int run = inc - sm;
  #pragma unroll
  for (int k = 0; k < 4; ++k) {
    int idx = t * 4 + k;
    if (idx < nb) { base[idx] = run; cursor[idx] = run; }
    run += v[k];
  }
  if (t == BLK - 1) base[nb] = E;
}

// bin edges into per-bucket segments, packed rec = (src<<8)|(dst&255)
// direct global write at placement (no stage, no binary search)
__global__ void k_bin(const int* __restrict__ src, const int* __restrict__ dst,
                      int* __restrict__ cursor, int* __restrict__ binned,
                      int E, int nb) {
  __shared__ int cnt[NBMAX], cur[NBMAX], gofs[NBMAX];
  int t = threadIdx.x;
  for (int i = t; i < NBMAX; i += BLK) { cnt[i] = 0; cur[i] = 0; }
  __syncthreads();
  long long s0 = (long long)blockIdx.x * CH;
  int c = (int)min((long long)CH, (long long)E - s0);
  for (int i = t; i < c; i += BLK) atomicAdd(&cnt[dst[s0 + i] >> 8], 1);
  __syncthreads();
  for (int b = t; b < nb; b += BLK)
    if (cnt[b]) gofs[b] = atomicAdd(&cursor[b], cnt[b]);
  __syncthreads();
  for (int i = t; i < c; i += BLK) {
    int d = dst[s0 + i];
    int b = d >> 8;
    int r = atomicAdd(&cur[b], 1);
    binned[(size_t)gofs[b] + r] = (src[s0 + i] << 8) | (d & 255);
  }
}

// per-bucket counting sort: binned run -> csr (per-node grouped), rowptr, dis
__global__ void k_sortdis(const int* __restrict__ base, const int* __restrict__ binned,
                          int* __restrict__ csr, int* __restrict__ rowptr,
                          float* __restrict__ dis, int n) {
  __shared__ int cnt[256], loff[256], cur[256], temp[BLK];
  int b = blockIdx.x, t = threadIdx.x;
  cnt[t] = 0; cur[t] = 0;
  __syncthreads();
  int s = base[b], e = base[b + 1];
  for (int i = s + t; i < e; i += BLK) atomicAdd(&cnt[binned[i] & 255], 1);
  __syncthreads();
  int v = cnt[t];
  temp[t] = v; __syncthreads();
  int inc = v;
  for (int off = 1; off < BLK; off <<= 1) {
    int u = (t >= off) ? temp[t - off] : 0; __syncthreads();
    inc += u; temp[t] = inc; __syncthreads();
  }
  loff[t] = inc - v;
  int node = b * 256 + t;
  if (node < n) {
    rowptr[node] = s + inc - v;
    dis[node] = rsqrtf((float)(v + 1));   // +1 self-loop
  }
  __syncthreads();
  for (int i = s + t; i < e; i += BLK) {
    int rec = binned[i];
    int L = rec & 255;
    int p = atomicAdd(&cur[L], 1);
    csr[s + loff[L] + p] = rec >> 8;      // scattered 4B inside 32KB window -> L2 absorbs
  }
}

// gather, wave-per-node: 64 lanes = 8 edges x 8 feats; shfl-reduce over edge slots
__global__ void k_gather(const int* __restrict__ rowptr, const int* __restrict__ csr,
                         const float* __restrict__ y, float* __restrict__ acc, int n) {
  int wid = (int)(((long long)blockIdx.x * BLK + threadIdx.x) >> 6);
  if (wid >= n) return;
  int lane = threadIdx.x & 63;
  int e = lane & 7, h = lane >> 3;
  int start = rowptr[wid], end = rowptr[wid + 1];
  float s = 0.f;
  int k0 = start;
  int k = k0 + e;
  int sidx = (k < end) ? csr[k] : -1;
  while (k0 < end) {
    int nk = k0 + 8 + e;
    int nsidx = (nk < end) ? csr[nk] : -1;   // prefetch next 8 sources
    if (sidx >= 0) s += y[(size_t)sidx * 8 + h];
    sidx = nsidx; k0 += 8;
  }
  s += __shfl_xor(s, 1);
  s += __shfl_xor(s, 2);
  s += __shfl_xor(s, 4);
  if (e == 0) acc[(size_t)wid * 8 + h] = s;
}

// ================= tier-2 fallback (R5 proven) =================

__global__ void k_degdis(const int* __restrict__ base, const int* __restrict__ binned,
                         float* __restrict__ dis, int n) {
  __shared__ int deg[256];
  int b = blockIdx.x, t = threadIdx.x;
  deg[t] = 1;
  __syncthreads();
  int s = base[b], e = base[b + 1];
  for (int i = s + t; i < e; i += BLK) atomicAdd(&deg[binned[i] & 255], 1);
  __syncthreads();
  int node = b * 256 + t;
  if (node < n) dis[node] = rsqrtf((float)deg[t]);
}

__global__ void k_acc(const int* __restrict__ base, const int* __restrict__ binned,
                      const float* __restrict__ y, float* __restrict__ acc, int n) {
  __shared__ float fa[2048];
  int b = blockIdx.x, t = threadIdx.x;
  for (int i = t; i < 2048; i += BLK) fa[i] = 0.f;
  __syncthreads();
  int s = base[b], e = base[b + 1];
  int j = t & 7;
  for (int i = s + (t >> 3); i < e; i += 32) {
    int rec = binned[i];
    atomicAdd(&fa[(rec & 255) * 8 + j], y[(size_t)(rec >> 8) * 8 + j]);
  }
  __syncthreads();
  int node0 = b * 256;
  int lim = (n - node0 < 256 ? n - node0 : 256) * 8;
  for (int i = t; i < lim; i += BLK) acc[(size_t)node0 * 8 + i] = fa[i];
}

// ================= dense stages =================

__global__ void k_y1n(const float* __restrict__ x, const float* __restrict__ W1,
                      const float* __restrict__ dis, float* __restrict__ y, int n) {
  __shared__ float sW[128];
  if (threadIdx.x < 128) sW[threadIdx.x] = W1[threadIdx.x];
  __syncthreads();
  int i = blockIdx.x * BLK + threadIdx.x;
  if (i >= n) return;
  const float4* xp = (const float4*)(x + (size_t)i * 16);
  float4 a = xp[0], bb = xp[1], cc = xp[2], d4 = xp[3];
  float xv[16] = {a.x,a.y,a.z,a.w, bb.x,bb.y,bb.z,bb.w,
                  cc.x,cc.y,cc.z,cc.w, d4.x,d4.y,d4.z,d4.w};
  float ds = dis[i];
  float o[8];
  #pragma unroll
  for (int jj = 0; jj < 8; ++jj) {
    float s = 0.f;
    #pragma unroll
    for (int k = 0; k < 16; ++k) s = fmaf(xv[k], sW[k*8 + jj], s);
    o[jj] = ds * s;
  }
  float4* yp = (float4*)(y + (size_t)i * 8);
  yp[0] = make_float4(o[0], o[1], o[2], o[3]);
  yp[1] = make_float4(o[4], o[5], o[6], o[7]);
}

__global__ void k_mid(const float* __restrict__ dis, float* __restrict__ y,
                      float* __restrict__ acc, const float* __restrict__ W2,
                      const float* __restrict__ b1, int n, int zero_acc) {
  __shared__ float sW[64];
  __shared__ float sb[8];
  if (threadIdx.x < 64) sW[threadIdx.x] = W2[threadIdx.x];
  if (threadIdx.x < 8)  sb[threadIdx.x] = b1[threadIdx.x];
  __syncthreads();
  int i = blockIdx.x * BLK + threadIdx.x;
  if (i >= n) return;
  float d = dis[i];
  float4* yp = (float4*)(y + (size_t)i * 8);
  float4* ap = (float4*)(acc + (size_t)i * 8);
  float4 y0 = yp[0], y1v = yp[1], a0 = ap[0], a1 = ap[1];
  float yy[8] = {y0.x,y0.y,y0.z,y0.w, y1v.x,y1v.y,y1v.z,y1v.w};
  float aa[8] = {a0.x,a0.y,a0.z,a0.w, a1.x,a1.y,a1.z,a1.w};
  float hv[8];
  #pragma unroll
  for (int jj = 0; jj < 8; ++jj) hv[jj] = fmaxf(fmaf(d, yy[jj] + aa[jj], sb[jj]), 0.f);
  float o[8];
  #pragma unroll
  for (int jj = 0; jj < 8; ++jj) {
    float s = 0.f;
    #pragma unroll
    for (int k = 0; k < 8; ++k) s = fmaf(hv[k], sW[k*8 + jj], s);
    o[jj] = d * s;
  }
  yp[0] = make_float4(o[0], o[1], o[2], o[3]);
  yp[1] = make_float4(o[4], o[5], o[6], o[7]);
  if (zero_acc) {
    ap[0] = make_float4(0.f, 0.f, 0.f, 0.f);
    ap[1] = make_float4(0.f, 0.f, 0.f, 0.f);
  }
}

__global__ void k_final(const float* __restrict__ dis, const float* __restrict__ y,
                        const float* __restrict__ acc, const float* __restrict__ b2,
                        const float* __restrict__ Wl, const int* __restrict__ batch,
                        float* __restrict__ zacc, int n) {
  __shared__ float sb[8], sw[8];
  if (threadIdx.x < 8) { sb[threadIdx.x] = b2[threadIdx.x]; sw[threadIdx.x] = Wl[threadIdx.x]; }
  __syncthreads();
  int i = blockIdx.x * BLK + threadIdx.x;
  float s = 0.f;
  int g = -1;
  if (i < n) {
    float d = dis[i];
    const float4* yp = (const float4*)(y + (size_t)i * 8);
    const float4* ap = (const float4*)(acc + (size_t)i * 8);
    float4 y0 = yp[0], y1v = yp[1], a0 = ap[0], a1 = ap[1];
    float yy[8] = {y0.x,y0.y,y0.z,y0.w, y1v.x,y1v.y,y1v.z,y1v.w};
    float aa[8] = {a0.x,a0.y,a0.z,a0.w, a1.x,a1.y,a1.z,a1.w};
    #pragma unroll
    for (int jj = 0; jj < 8; ++jj) {
      float h = fmaxf(fmaf(d, yy[jj] + aa[jj], sb[jj]), 0.f);
      s = fmaf(h, sw[jj], s);
    }
    g = batch[i];
  }
  int g0 = __shfl(g, 0);
  bool uni = __all(g == g0);
  if (uni) {
    #pragma unroll
    for (int off = 32; off > 0; off >>= 1) s += __shfl_down(s, off);
    if ((threadIdx.x & 63) == 0 && g0 >= 0) unsafeAtomicAdd(&zacc[g0], s);
  } else if (i < n) {
    unsafeAtomicAdd(&zacc[g], s);
  }
}

__global__ void k_out(const float* __restrict__ zacc, const float* __restrict__ bl,
                      float* __restrict__ out, int ng) {
  int i = blockIdx.x * BLK + threadIdx.x;
  if (i < ng) {
    float z = zacc[i] + bl[0];
    float r;
    if (z >= 0.f) { r = 1.f / (1.f + expf(-z)); }
    else          { float e = expf(z); r = e / (1.f + e); }
    out[i] = r;
  }
}

// ================= tier-3 fallback (R2 proven) =================

__global__ void k_init(int* __restrict__ deg, float* __restrict__ acc,
                       float* __restrict__ zacc, int n, int accn, int ng) {
  int jj = blockIdx.x * BLK + threadIdx.x;
  if (jj < accn) acc[jj] = 0.f;
  if (jj < n) deg[jj] = 1;
  if (jj < ng) zacc[jj] = 0.f;
}

__global__ void k_deg(const int* __restrict__ dst, int* __restrict__ deg, int E) {
  int i = blockIdx.x * BLK + threadIdx.x;
  if (i < E) atomicAdd(&deg[dst[i]], 1);
}

__global__ void k_y1(const float* __restrict__ x, const float* __restrict__ W1,
                     int* __restrict__ degdis, float* __restrict__ y, int n) {
  __shared__ float sW[128];
  if (threadIdx.x < 128) sW[threadIdx.x] = W1[threadIdx.x];
  __syncthreads();
  int i = blockIdx.x * BLK + threadIdx.x;
  if (i >= n) return;
  const float4* xp = (const float4*)(x + (size_t)i * 16);
  float4 a = xp[0], bb = xp[1], cc = xp[2], d4 = xp[3];
  float xv[16] = {a.x,a.y,a.z,a.w, bb.x,bb.y,bb.z,bb.w,
                  cc.x,cc.y,cc.z,cc.w, d4.x,d4.y,d4.z,d4.w};
  float ds = rsqrtf((float)degdis[i]);
  float o[8];
  #pragma unroll
  for (int jj = 0; jj < 8; ++jj) {
    float s = 0.f;
    #pragma unroll
    for (int k = 0; k < 16; ++k) s = fmaf(xv[k], sW[k*8 + jj], s);
    o[jj] = ds * s;
  }
  ((float*)degdis)[i] = ds;
  float4* yp = (float4*)(y + (size_t)i * 8);
  yp[0] = make_float4(o[0], o[1], o[2], o[3]);
  yp[1] = make_float4(o[4], o[5], o[6], o[7]);
}

__global__ void k_scatter(const int* __restrict__ src, const int* __restrict__ dst,
                          const float* __restrict__ y, float* __restrict__ acc,
                          long long total) {
  long long t = (long long)blockIdx.x * BLK + threadIdx.x;
  if (t >= total) return;
  int e = (int)(t >> 3);
  int h = (int)(t & 7);
  int s = src[e], d = dst[e];
  unsafeAtomicAdd(&acc[(size_t)d * 8 + h], y[(size_t)s * 8 + h]);
}

// ================= host =================

static inline size_t alignup(size_t v) { return (v + 255) & ~(size_t)255; }

extern "C" void kernel_launch(void* const* d_in, const int* in_sizes, int n_in,
                              void* d_out, int out_size, void* d_ws, size_t ws_size,
                              hipStream_t stream) {
  const float* x   = (const float*)d_in[0];
  const int*   ei  = (const int*)  d_in[1];
  const int*   bat = (const int*)  d_in[2];
  const float* W1  = (const float*)d_in[3];
  const float* b1  = (const float*)d_in[4];
  const float* W2  = (const float*)d_in[5];
  const float* b2  = (const float*)d_in[6];
  const float* Wl  = (const float*)d_in[7];
  const float* bl  = (const float*)d_in[8];
  float* out = (float*)d_out;

  int n  = in_sizes[0] / 16;   // 250000
  int E  = in_sizes[1] / 2;    // 8000000
  int ng = out_size;           // 512

  const int* src = ei;
  const int* dst = ei + E;

  int nb = (n + 255) >> 8;     // 977

  char* wsb = (char*)d_ws;
  size_t offY  = alignup((size_t)n * 4);                  // dis
  size_t offA  = offY + alignup((size_t)n * 8 * 4);       // y
  size_t offZ  = offA + alignup((size_t)n * 8 * 4);       // acc
  size_t offH  = offZ + alignup((size_t)ng * 4);          // zacc
  size_t offB  = offH + alignup((size_t)NBMAX * 4);       // ghist
  size_t offCu = offB + alignup((size_t)(NBMAX + 1) * 4); // base
  size_t offBn = offCu + alignup((size_t)NBMAX * 4);      // cursor
  size_t offRp = offBn + alignup((size_t)E * 4);          // binned
  size_t offCs = offRp + alignup(((size_t)n + 1) * 4);    // rowptr
  size_t need1 = offCs + alignup((size_t)E * 4);          // csr
  size_t need2 = offRp;                                   // tier-2: through binned

  float* dis    = (float*)wsb;
  int*   deg    = (int*)wsb;
  float* y      = (float*)(wsb + offY);
  float* acc    = (float*)(wsb + offA);
  float* zacc   = (float*)(wsb + offZ);
  int*   ghist  = (int*)(wsb + offH);
  int*   base   = (int*)(wsb + offB);
  int*   cursor = (int*)(wsb + offCu);
  int*   binned = (int*)(wsb + offBn);
  int*   rowptr = (int*)(wsb + offRp);
  int*   csr    = (int*)(wsb + offCs);

  int gN = (n + BLK - 1) / BLK;
  int gG = (ng + BLK - 1) / BLK;
  int gW = (int)(((long long)n * 64 + BLK - 1) / BLK);   // wave-per-node gather

  bool ok_bin = (nb <= NBMAX) && (n < (1 << 23));
  bool tier1 = ok_bin && (ws_size >= need1);
  bool tier2 = ok_bin && (ws_size >= need2);

  if (tier1 || tier2) {
    int histChunk = 15625;
    int gHist = (int)(((long long)E + histChunk - 1) / histChunk);
    int gBin  = (int)(((long long)E + CH - 1) / CH);
    int gI0   = (NBMAX > ng ? NBMAX : ng) / BLK + 1;
    k_init0 <<<gI0, BLK, 0, stream>>>(ghist, zacc, rowptr, NBMAX, ng, n, E, tier1 ? 1 : 0);
    k_hist  <<<gHist, BLK, 0, stream>>>(dst, ghist, E, nb, histChunk);
    k_scan  <<<1, BLK, 0, stream>>>(ghist, base, cursor, nb, E);
    k_bin   <<<gBin, BLK, 0, stream>>>(src, dst, cursor, binned, E, nb);
    if (tier1) {
      k_sortdis<<<nb, BLK, 0, stream>>>(base, binned, csr, rowptr, dis, n);
      k_y1n   <<<gN, BLK, 0, stream>>>(x, W1, dis, y, n);
      k_gather<<<gW, BLK, 0, stream>>>(rowptr, csr, y, acc, n);
      k_mid   <<<gN, BLK, 0, stream>>>(dis, y, acc, W2, b1, n, 0);
      k_gather<<<gW, BLK, 0, stream>>>(rowptr, csr, y, acc, n);
    } else {
      k_degdis<<<nb, BLK, 0, stream>>>(base, binned, dis, n);
      k_y1n   <<<gN, BLK, 0, stream>>>(x, W1, dis, y, n);
      k_acc   <<<nb, BLK, 0, stream>>>(base, binned, y, acc, n);
      k_mid   <<<gN, BLK, 0, stream>>>(dis, y, acc, W2, b1, n, 0);
      k_acc   <<<nb, BLK, 0, stream>>>(base, binned, y, acc, n);
    }
    k_final <<<gN, BLK, 0, stream>>>(dis, y, acc, b2, Wl, bat, zacc, n);
  } else {
    int accn = n * 8;
    long long tot = (long long)E * 8;
    int gInit = (accn + BLK - 1) / BLK;
    int gE    = (E + BLK - 1) / BLK;
    int gS    = (int)((tot + BLK - 1) / BLK);
    k_init   <<<gInit, BLK, 0, stream>>>(deg, acc, zacc, n, accn, ng);
    k_deg    <<<gE, BLK, 0, stream>>>(dst, deg, E);
    k_y1     <<<gN, BLK, 0, stream>>>(x, W1, deg, y, n);
    k_scatter<<<gS, BLK, 0, stream>>>(src, dst, y, acc, tot);
    k_mid    <<<gN, BLK, 0, stream>>>(dis, y, acc, W2, b1, n, 1);
    k_scatter<<<gS, BLK, 0, stream>>>(src, dst, y, acc, tot);
    k_final  <<<gN, BLK, 0, stream>>>(dis, y, acc, b2, Wl, bat, zacc, n);
  }
  k_out<<<gG, BLK, 0, stream>>>(zacc, bl, out, ng);
}

// Round 8
// 538.792 us; speedup vs baseline: 1.0196x; 1.0196x over previous
//
#include <hip/hip_runtime.h>
#include <math.h>

#define BLK 256
#define CH 4096          // edges per k_bin block (staged)
#define NBMAX 1024       // max buckets (256 nodes each)

// ================= binned + CSR path =================

// zero ghist + zacc; rowptr[n] = E
__global__ void k_init0(int* __restrict__ ghist, float* __restrict__ zacc,
                        int* __restrict__ rowptr, int nb, int ng, int n, int E,
                        int primary) {
  int i = blockIdx.x * BLK + threadIdx.x;
  if (i < nb) ghist[i] = 0;
  if (i < ng) zacc[i] = 0.f;
  if (primary && i == 0) rowptr[n] = E;
}

// per-bucket histogram of dst>>8
__global__ void k_hist(const int* __restrict__ dst, int* __restrict__ ghist,
                       int E, int nb, int chunk) {
  __shared__ int h[NBMAX];
  for (int i = threadIdx.x; i < NBMAX; i += BLK) h[i] = 0;
  __syncthreads();
  long long s0 = (long long)blockIdx.x * chunk;
  int c = (int)min((long long)chunk, (long long)E - s0);
  for (int i = threadIdx.x; i < c; i += BLK)
    atomicAdd(&h[dst[s0 + i] >> 8], 1);
  __syncthreads();
  for (int b = threadIdx.x; b < nb; b += BLK)
    if (h[b]) atomicAdd(&ghist[b], h[b]);
}

// exclusive scan of ghist -> base[0..nb], cursor=base
__global__ void k_scan(const int* __restrict__ ghist, int* __restrict__ base,
                       int* __restrict__ cursor, int nb, int E) {
  __shared__ int temp[BLK];
  int t = threadIdx.x;
  int v[4]; int sm = 0;
  #pragma unroll
  for (int k = 0; k < 4; ++k) {
    int idx = t * 4 + k;
    v[k] = (idx < nb) ? ghist[idx] : 0;
    sm += v[k];
  }
  temp[t] = sm; __syncthreads();
  int inc = sm;
  for (int off = 1; off < BLK; off <<= 1) {
    int u = (t >= off) ? temp[t - off] : 0; __syncthreads();
    inc += u; temp[t] = inc; __syncthreads();
  }
  int run = inc - sm;
  #pragma unroll
  for (int k = 0; k < 4; ++k) {
    int idx = t * 4 + k;
    if (idx < nb) { base[idx] = run; cursor[idx] = run; }
    run += v[k];
  }
  if (t == BLK - 1) base[nb] = E;
}

// bin edges into per-bucket segments, packed rec = (src<<8)|(dst&255)
// staged in LDS so the global flush writes contiguous per-bucket runs
__global__ void k_bin(const int* __restrict__ src, const int* __restrict__ dst,
                      int* __restrict__ cursor, int* __restrict__ binned,
                      int E, int nb) {
  __shared__ int cnt[NBMAX], cur[NBMAX], gofs[NBMAX], baseA[NBMAX + 1], temp[BLK];
  __shared__ int stage[CH];
  int t = threadIdx.x;
  for (int i = t; i < NBMAX; i += BLK) { cnt[i] = 0; cur[i] = 0; }
  __syncthreads();
  long long s0 = (long long)blockIdx.x * CH;
  int c = (int)min((long long)CH, (long long)E - s0);
  for (int i = t; i < c; i += BLK) atomicAdd(&cnt[dst[s0 + i] >> 8], 1);
  __syncthreads();
  int v[4], sm = 0;
  #pragma unroll
  for (int k = 0; k < 4; ++k) { v[k] = cnt[t * 4 + k]; sm += v[k]; }
  temp[t] = sm; __syncthreads();
  int inc = sm;
  for (int off = 1; off < BLK; off <<= 1) {
    int u = (t >= off) ? temp[t - off] : 0; __syncthreads();
    inc += u; temp[t] = inc; __syncthreads();
  }
  int run = inc - sm;
  #pragma unroll
  for (int k = 0; k < 4; ++k) { baseA[t * 4 + k] = run; run += v[k]; }
  if (t == BLK - 1) baseA[NBMAX] = c;
  __syncthreads();
  for (int b = t; b < nb; b += BLK)
    if (cnt[b]) gofs[b] = atomicAdd(&cursor[b], cnt[b]);
  __syncthreads();
  for (int i = t; i < c; i += BLK) {
    int d = dst[s0 + i];
    int b = d >> 8;
    int r = atomicAdd(&cur[b], 1);
    stage[baseA[b] + r] = (src[s0 + i] << 8) | (d & 255);
  }
  __syncthreads();
  // flush in stage order: consecutive lanes -> consecutive global slots per run
  for (int i = t; i < c; i += BLK) {
    int lo = 0, hi = nb;
    while (hi - lo > 1) { int m = (lo + hi) >> 1; if (baseA[m] <= i) lo = m; else hi = m; }
    binned[(size_t)gofs[lo] + (i - baseA[lo])] = stage[i];
  }
}

// per-bucket counting sort: binned run -> csr (per-node grouped), rowptr, dis
__global__ void k_sortdis(const int* __restrict__ base, const int* __restrict__ binned,
                          int* __restrict__ csr, int* __restrict__ rowptr,
                          float* __restrict__ dis, int n) {
  __shared__ int cnt[256], loff[256], cur[256], temp[BLK];
  int b = blockIdx.x, t = threadIdx.x;
  cnt[t] = 0; cur[t] = 0;
  __syncthreads();
  int s = base[b], e = base[b + 1];
  for (int i = s + t; i < e; i += BLK) atomicAdd(&cnt[binned[i] & 255], 1);
  __syncthreads();
  int v = cnt[t];
  temp[t] = v; __syncthreads();
  int inc = v;
  for (int off = 1; off < BLK; off <<= 1) {
    int u = (t >= off) ? temp[t - off] : 0; __syncthreads();
    inc += u; temp[t] = inc; __syncthreads();
  }
  loff[t] = inc - v;
  int node = b * 256 + t;
  if (node < n) {
    rowptr[node] = s + inc - v;
    dis[node] = rsqrtf((float)(v + 1));   // +1 self-loop
  }
  __syncthreads();
  for (int i = s + t; i < e; i += BLK) {
    int rec = binned[i];
    int L = rec & 255;
    int p = atomicAdd(&cur[L], 1);
    csr[s + loff[L] + p] = rec >> 8;
  }
}

// gather, wave-per-node: 64 lanes = 8 edges x 8 feats; shfl-reduce over edge slots
__global__ void k_gather(const int* __restrict__ rowptr, const int* __restrict__ csr,
                         const float* __restrict__ y, float* __restrict__ acc, int n) {
  int wid = (int)(((long long)blockIdx.x * BLK + threadIdx.x) >> 6);
  if (wid >= n) return;
  int lane = threadIdx.x & 63;
  int e = lane & 7, h = lane >> 3;
  int start = rowptr[wid], end = rowptr[wid + 1];
  float s = 0.f;
  int k0 = start;
  int k = k0 + e;
  int sidx = (k < end) ? csr[k] : -1;
  while (k0 < end) {
    int nk = k0 + 8 + e;
    int nsidx = (nk < end) ? csr[nk] : -1;   // prefetch next 8 sources
    if (sidx >= 0) s += y[(size_t)sidx * 8 + h];
    sidx = nsidx; k0 += 8;
  }
  s += __shfl_xor(s, 1);
  s += __shfl_xor(s, 2);
  s += __shfl_xor(s, 4);
  if (e == 0) acc[(size_t)wid * 8 + h] = s;
}

// ================= tier-2 fallback (R5 proven) =================

__global__ void k_degdis(const int* __restrict__ base, const int* __restrict__ binned,
                         float* __restrict__ dis, int n) {
  __shared__ int deg[256];
  int b = blockIdx.x, t = threadIdx.x;
  deg[t] = 1;
  __syncthreads();
  int s = base[b], e = base[b + 1];
  for (int i = s + t; i < e; i += BLK) atomicAdd(&deg[binned[i] & 255], 1);
  __syncthreads();
  int node = b * 256 + t;
  if (node < n) dis[node] = rsqrtf((float)deg[t]);
}

__global__ void k_acc(const int* __restrict__ base, const int* __restrict__ binned,
                      const float* __restrict__ y, float* __restrict__ acc, int n) {
  __shared__ float fa[2048];
  int b = blockIdx.x, t = threadIdx.x;
  for (int i = t; i < 2048; i += BLK) fa[i] = 0.f;
  __syncthreads();
  int s = base[b], e = base[b + 1];
  int j = t & 7;
  for (int i = s + (t >> 3); i < e; i += 32) {
    int rec = binned[i];
    atomicAdd(&fa[(rec & 255) * 8 + j], y[(size_t)(rec >> 8) * 8 + j]);
  }
  __syncthreads();
  int node0 = b * 256;
  int lim = (n - node0 < 256 ? n - node0 : 256) * 8;
  for (int i = t; i < lim; i += BLK) acc[(size_t)node0 * 8 + i] = fa[i];
}

// ================= dense stages =================

__global__ void k_y1n(const float* __restrict__ x, const float* __restrict__ W1,
                      const float* __restrict__ dis, float* __restrict__ y, int n) {
  __shared__ float sW[128];
  if (threadIdx.x < 128) sW[threadIdx.x] = W1[threadIdx.x];
  __syncthreads();
  int i = blockIdx.x * BLK + threadIdx.x;
  if (i >= n) return;
  const float4* xp = (const float4*)(x + (size_t)i * 16);
  float4 a = xp[0], bb = xp[1], cc = xp[2], d4 = xp[3];
  float xv[16] = {a.x,a.y,a.z,a.w, bb.x,bb.y,bb.z,bb.w,
                  cc.x,cc.y,cc.z,cc.w, d4.x,d4.y,d4.z,d4.w};
  float ds = dis[i];
  float o[8];
  #pragma unroll
  for (int jj = 0; jj < 8; ++jj) {
    float s = 0.f;
    #pragma unroll
    for (int k = 0; k < 16; ++k) s = fmaf(xv[k], sW[k*8 + jj], s);
    o[jj] = ds * s;
  }
  float4* yp = (float4*)(y + (size_t)i * 8);
  yp[0] = make_float4(o[0], o[1], o[2], o[3]);
  yp[1] = make_float4(o[4], o[5], o[6], o[7]);
}

__global__ void k_mid(const float* __restrict__ dis, float* __restrict__ y,
                      float* __restrict__ acc, const float* __restrict__ W2,
                      const float* __restrict__ b1, int n, int zero_acc) {
  __shared__ float sW[64];
  __shared__ float sb[8];
  if (threadIdx.x < 64) sW[threadIdx.x] = W2[threadIdx.x];
  if (threadIdx.x < 8)  sb[threadIdx.x] = b1[threadIdx.x];
  __syncthreads();
  int i = blockIdx.x * BLK + threadIdx.x;
  if (i >= n) return;
  float d = dis[i];
  float4* yp = (float4*)(y + (size_t)i * 8);
  float4* ap = (float4*)(acc + (size_t)i * 8);
  float4 y0 = yp[0], y1v = yp[1], a0 = ap[0], a1 = ap[1];
  float yy[8] = {y0.x,y0.y,y0.z,y0.w, y1v.x,y1v.y,y1v.z,y1v.w};
  float aa[8] = {a0.x,a0.y,a0.z,a0.w, a1.x,a1.y,a1.z,a1.w};
  float hv[8];
  #pragma unroll
  for (int jj = 0; jj < 8; ++jj) hv[jj] = fmaxf(fmaf(d, yy[jj] + aa[jj], sb[jj]), 0.f);
  float o[8];
  #pragma unroll
  for (int jj = 0; jj < 8; ++jj) {
    float s = 0.f;
    #pragma unroll
    for (int k = 0; k < 8; ++k) s = fmaf(hv[k], sW[k*8 + jj], s);
    o[jj] = d * s;
  }
  yp[0] = make_float4(o[0], o[1], o[2], o[3]);
  yp[1] = make_float4(o[4], o[5], o[6], o[7]);
  if (zero_acc) {
    ap[0] = make_float4(0.f, 0.f, 0.f, 0.f);
    ap[1] = make_float4(0.f, 0.f, 0.f, 0.f);
  }
}

__global__ void k_final(const float* __restrict__ dis, const float* __restrict__ y,
                        const float* __restrict__ acc, const float* __restrict__ b2,
                        const float* __restrict__ Wl, const int* __restrict__ batch,
                        float* __restrict__ zacc, int n) {
  __shared__ float sb[8], sw[8];
  if (threadIdx.x < 8) { sb[threadIdx.x] = b2[threadIdx.x]; sw[threadIdx.x] = Wl[threadIdx.x]; }
  __syncthreads();
  int i = blockIdx.x * BLK + threadIdx.x;
  float s = 0.f;
  int g = -1;
  if (i < n) {
    float d = dis[i];
    const float4* yp = (const float4*)(y + (size_t)i * 8);
    const float4* ap = (const float4*)(acc + (size_t)i * 8);
    float4 y0 = yp[0], y1v = yp[1], a0 = ap[0], a1 = ap[1];
    float yy[8] = {y0.x,y0.y,y0.z,y0.w, y1v.x,y1v.y,y1v.z,y1v.w};
    float aa[8] = {a0.x,a0.y,a0.z,a0.w, a1.x,a1.y,a1.z,a1.w};
    #pragma unroll
    for (int jj = 0; jj < 8; ++jj) {
      float h = fmaxf(fmaf(d, yy[jj] + aa[jj], sb[jj]), 0.f);
      s = fmaf(h, sw[jj], s);
    }
    g = batch[i];
  }
  int g0 = __shfl(g, 0);
  bool uni = __all(g == g0);
  if (uni) {
    #pragma unroll
    for (int off = 32; off > 0; off >>= 1) s += __shfl_down(s, off);
    if ((threadIdx.x & 63) == 0 && g0 >= 0) unsafeAtomicAdd(&zacc[g0], s);
  } else if (i < n) {
    unsafeAtomicAdd(&zacc[g], s);
  }
}

__global__ void k_out(const float* __restrict__ zacc, const float* __restrict__ bl,
                      float* __restrict__ out, int ng) {
  int i = blockIdx.x * BLK + threadIdx.x;
  if (i < ng) {
    float z = zacc[i] + bl[0];
    float r;
    if (z >= 0.f) { r = 1.f / (1.f + expf(-z)); }
    else          { float e = expf(z); r = e / (1.f + e); }
    out[i] = r;
  }
}

// ================= tier-3 fallback (R2 proven) =================

__global__ void k_init(int* __restrict__ deg, float* __restrict__ acc,
                       float* __restrict__ zacc, int n, int accn, int ng) {
  int jj = blockIdx.x * BLK + threadIdx.x;
  if (jj < accn) acc[jj] = 0.f;
  if (jj < n) deg[jj] = 1;
  if (jj < ng) zacc[jj] = 0.f;
}

__global__ void k_deg(const int* __restrict__ dst, int* __restrict__ deg, int E) {
  int i = blockIdx.x * BLK + threadIdx.x;
  if (i < E) atomicAdd(&deg[dst[i]], 1);
}

__global__ void k_y1(const float* __restrict__ x, const float* __restrict__ W1,
                     int* __restrict__ degdis, float* __restrict__ y, int n) {
  __shared__ float sW[128];
  if (threadIdx.x < 128) sW[threadIdx.x] = W1[threadIdx.x];
  __syncthreads();
  int i = blockIdx.x * BLK + threadIdx.x;
  if (i >= n) return;
  const float4* xp = (const float4*)(x + (size_t)i * 16);
  float4 a = xp[0], bb = xp[1], cc = xp[2], d4 = xp[3];
  float xv[16] = {a.x,a.y,a.z,a.w, bb.x,bb.y,bb.z,bb.w,
                  cc.x,cc.y,cc.z,cc.w, d4.x,d4.y,d4.z,d4.w};
  float ds = rsqrtf((float)degdis[i]);
  float o[8];
  #pragma unroll
  for (int jj = 0; jj < 8; ++jj) {
    float s = 0.f;
    #pragma unroll
    for (int k = 0; k < 16; ++k) s = fmaf(xv[k], sW[k*8 + jj], s);
    o[jj] = ds * s;
  }
  ((float*)degdis)[i] = ds;
  float4* yp = (float4*)(y + (size_t)i * 8);
  yp[0] = make_float4(o[0], o[1], o[2], o[3]);
  yp[1] = make_float4(o[4], o[5], o[6], o[7]);
}

__global__ void k_scatter(const int* __restrict__ src, const int* __restrict__ dst,
                          const float* __restrict__ y, float* __restrict__ acc,
                          long long total) {
  long long t = (long long)blockIdx.x * BLK + threadIdx.x;
  if (t >= total) return;
  int e = (int)(t >> 3);
  int h = (int)(t & 7);
  int s = src[e], d = dst[e];
  unsafeAtomicAdd(&acc[(size_t)d * 8 + h], y[(size_t)s * 8 + h]);
}

// ================= host =================

static inline size_t alignup(size_t v) { return (v + 255) & ~(size_t)255; }

extern "C" void kernel_launch(void* const* d_in, const int* in_sizes, int n_in,
                              void* d_out, int out_size, void* d_ws, size_t ws_size,
                              hipStream_t stream) {
  const float* x   = (const float*)d_in[0];
  const int*   ei  = (const int*)  d_in[1];
  const int*   bat = (const int*)  d_in[2];
  const float* W1  = (const float*)d_in[3];
  const float* b1  = (const float*)d_in[4];
  const float* W2  = (const float*)d_in[5];
  const float* b2  = (const float*)d_in[6];
  const float* Wl  = (const float*)d_in[7];
  const float* bl  = (const float*)d_in[8];
  float* out = (float*)d_out;

  int n  = in_sizes[0] / 16;   // 250000
  int E  = in_sizes[1] / 2;    // 8000000
  int ng = out_size;           // 512

  const int* src = ei;
  const int* dst = ei + E;

  int nb = (n + 255) >> 8;     // 977

  char* wsb = (char*)d_ws;
  size_t offY  = alignup((size_t)n * 4);                  // dis
  size_t offA  = offY + alignup((size_t)n * 8 * 4);       // y
  size_t offZ  = offA + alignup((size_t)n * 8 * 4);       // acc
  size_t offH  = offZ + alignup((size_t)ng * 4);          // zacc
  size_t offB  = offH + alignup((size_t)NBMAX * 4);       // ghist
  size_t offCu = offB + alignup((size_t)(NBMAX + 1) * 4); // base
  size_t offBn = offCu + alignup((size_t)NBMAX * 4);      // cursor
  size_t offRp = offBn + alignup((size_t)E * 4);          // binned
  size_t offCs = offRp + alignup(((size_t)n + 1) * 4);    // rowptr
  size_t need1 = offCs + alignup((size_t)E * 4);          // csr
  size_t need2 = offRp;                                   // tier-2: through binned

  float* dis    = (float*)wsb;
  int*   deg    = (int*)wsb;
  float* y      = (float*)(wsb + offY);
  float* acc    = (float*)(wsb + offA);
  float* zacc   = (float*)(wsb + offZ);
  int*   ghist  = (int*)(wsb + offH);
  int*   base   = (int*)(wsb + offB);
  int*   cursor = (int*)(wsb + offCu);
  int*   binned = (int*)(wsb + offBn);
  int*   rowptr = (int*)(wsb + offRp);
  int*   csr    = (int*)(wsb + offCs);

  int gN = (n + BLK - 1) / BLK;
  int gG = (ng + BLK - 1) / BLK;
  int gW = (int)(((long long)n * 64 + BLK - 1) / BLK);   // wave-per-node gather

  bool ok_bin = (nb <= NBMAX) && (n < (1 << 23));
  bool tier1 = ok_bin && (ws_size >= need1);
  bool tier2 = ok_bin && (ws_size >= need2);

  if (tier1 || tier2) {
    int histChunk = 4096;
    int gHist = (int)(((long long)E + histChunk - 1) / histChunk);
    int gBin  = (int)(((long long)E + CH - 1) / CH);
    int gI0   = (NBMAX > ng ? NBMAX : ng) / BLK + 1;
    k_init0 <<<gI0, BLK, 0, stream>>>(ghist, zacc, rowptr, NBMAX, ng, n, E, tier1 ? 1 : 0);
    k_hist  <<<gHist, BLK, 0, stream>>>(dst, ghist, E, nb, histChunk);
    k_scan  <<<1, BLK, 0, stream>>>(ghist, base, cursor, nb, E);
    k_bin   <<<gBin, BLK, 0, stream>>>(src, dst, cursor, binned, E, nb);
    if (tier1) {
      k_sortdis<<<nb, BLK, 0, stream>>>(base, binned, csr, rowptr, dis, n);
      k_y1n   <<<gN, BLK, 0, stream>>>(x, W1, dis, y, n);
      k_gather<<<gW, BLK, 0, stream>>>(rowptr, csr, y, acc, n);
      k_mid   <<<gN, BLK, 0, stream>>>(dis, y, acc, W2, b1, n, 0);
      k_gather<<<gW, BLK, 0, stream>>>(rowptr, csr, y, acc, n);
    } else {
      k_degdis<<<nb, BLK, 0, stream>>>(base, binned, dis, n);
      k_y1n   <<<gN, BLK, 0, stream>>>(x, W1, dis, y, n);
      k_acc   <<<nb, BLK, 0, stream>>>(base, binned, y, acc, n);
      k_mid   <<<gN, BLK, 0, stream>>>(dis, y, acc, W2, b1, n, 0);
      k_acc   <<<nb, BLK, 0, stream>>>(base, binned, y, acc, n);
    }
    k_final <<<gN, BLK, 0, stream>>>(dis, y, acc, b2, Wl, bat, zacc, n);
  } else {
    int accn = n * 8;
    long long tot = (long long)E * 8;
    int gInit = (accn + BLK - 1) / BLK;
    int gE    = (E + BLK - 1) / BLK;
    int gS    = (int)((tot + BLK - 1) / BLK);
    k_init   <<<gInit, BLK, 0, stream>>>(deg, acc, zacc, n, accn, ng);
    k_deg    <<<gE, BLK, 0, stream>>>(dst, deg, E);
    k_y1     <<<gN, BLK, 0, stream>>>(x, W1, deg, y, n);
    k_scatter<<<gS, BLK, 0, stream>>>(src, dst, y, acc, tot);
    k_mid    <<<gN, BLK, 0, stream>>>(dis, y, acc, W2, b1, n, 1);
    k_scatter<<<gS, BLK, 0, stream>>>(src, dst, y, acc, tot);
    k_final  <<<gN, BLK, 0, stream>>>(dis, y, acc, b2, Wl, bat, zacc, n);
  }
  k_out<<<gG, BLK, 0, stream>>>(zacc, bl, out, ng);
}

// Round 9
// 448.029 us; speedup vs baseline: 1.2261x; 1.2026x over previous
//
#include <hip/hip_runtime.h>
#include <math.h>

#define BLK 256
#define CH 4096          // edges per k_bin block (staged)
#define NBMAX 1024       // max buckets (256 nodes each)

// ================= binned + CSR path =================

// zero ghist + zacc; rowptr[n] = E
__global__ void k_init0(int* __restrict__ ghist, float* __restrict__ zacc,
                        int* __restrict__ rowptr, int nb, int ng, int n, int E,
                        int primary) {
  int i = blockIdx.x * BLK + threadIdx.x;
  if (i < nb) ghist[i] = 0;
  if (i < ng) zacc[i] = 0.f;
  if (primary && i == 0) rowptr[n] = E;
}

// per-bucket histogram of dst>>8
__global__ void k_hist(const int* __restrict__ dst, int* __restrict__ ghist,
                       int E, int nb, int chunk) {
  __shared__ int h[NBMAX];
  for (int i = threadIdx.x; i < NBMAX; i += BLK) h[i] = 0;
  __syncthreads();
  long long s0 = (long long)blockIdx.x * chunk;
  int c = (int)min((long long)chunk, (long long)E - s0);
  for (int i = threadIdx.x; i < c; i += BLK)
    atomicAdd(&h[dst[s0 + i] >> 8], 1);
  __syncthreads();
  for (int b = threadIdx.x; b < nb; b += BLK)
    if (h[b]) atomicAdd(&ghist[b], h[b]);
}

// exclusive scan of ghist -> base[0..nb], cursor=base
__global__ void k_scan(const int* __restrict__ ghist, int* __restrict__ base,
                       int* __restrict__ cursor, int nb, int E) {
  __shared__ int temp[BLK];
  int t = threadIdx.x;
  int v[4]; int sm = 0;
  #pragma unroll
  for (int k = 0; k < 4; ++k) {
    int idx = t * 4 + k;
    v[k] = (idx < nb) ? ghist[idx] : 0;
    sm += v[k];
  }
  temp[t] = sm; __syncthreads();
  int inc = sm;
  for (int off = 1; off < BLK; off <<= 1) {
    int u = (t >= off) ? temp[t - off] : 0; __syncthreads();
    inc += u; temp[t] = inc; __syncthreads();
  }
  int run = inc - sm;
  #pragma unroll
  for (int k = 0; k < 4; ++k) {
    int idx = t * 4 + k;
    if (idx < nb) { base[idx] = run; cursor[idx] = run; }
    run += v[k];
  }
  if (t == BLK - 1) base[nb] = E;
}

// bin edges into per-bucket segments, packed rec = (src<<8)|(dst&255)
// staged in LDS so the global flush writes contiguous per-bucket runs
__global__ void k_bin(const int* __restrict__ src, const int* __restrict__ dst,
                      int* __restrict__ cursor, int* __restrict__ binned,
                      int E, int nb) {
  __shared__ int cnt[NBMAX], cur[NBMAX], gofs[NBMAX], baseA[NBMAX + 1], temp[BLK];
  __shared__ int stage[CH];
  int t = threadIdx.x;
  for (int i = t; i < NBMAX; i += BLK) { cnt[i] = 0; cur[i] = 0; }
  __syncthreads();
  long long s0 = (long long)blockIdx.x * CH;
  int c = (int)min((long long)CH, (long long)E - s0);
  for (int i = t; i < c; i += BLK) atomicAdd(&cnt[dst[s0 + i] >> 8], 1);
  __syncthreads();
  int v[4], sm = 0;
  #pragma unroll
  for (int k = 0; k < 4; ++k) { v[k] = cnt[t * 4 + k]; sm += v[k]; }
  temp[t] = sm; __syncthreads();
  int inc = sm;
  for (int off = 1; off < BLK; off <<= 1) {
    int u = (t >= off) ? temp[t - off] : 0; __syncthreads();
    inc += u; temp[t] = inc; __syncthreads();
  }
  int run = inc - sm;
  #pragma unroll
  for (int k = 0; k < 4; ++k) { baseA[t * 4 + k] = run; run += v[k]; }
  if (t == BLK - 1) baseA[NBMAX] = c;
  __syncthreads();
  for (int b = t; b < nb; b += BLK)
    if (cnt[b]) gofs[b] = atomicAdd(&cursor[b], cnt[b]);
  __syncthreads();
  for (int i = t; i < c; i += BLK) {
    int d = dst[s0 + i];
    int b = d >> 8;
    int r = atomicAdd(&cur[b], 1);
    stage[baseA[b] + r] = (src[s0 + i] << 8) | (d & 255);
  }
  __syncthreads();
  // flush in stage order: consecutive lanes -> consecutive global slots per run
  for (int i = t; i < c; i += BLK) {
    int lo = 0, hi = nb;
    while (hi - lo > 1) { int m = (lo + hi) >> 1; if (baseA[m] <= i) lo = m; else hi = m; }
    binned[(size_t)gofs[lo] + (i - baseA[lo])] = stage[i];
  }
}

// per-bucket counting sort: binned run -> csr (per-node grouped), rowptr, dis
__global__ void k_sortdis(const int* __restrict__ base, const int* __restrict__ binned,
                          int* __restrict__ csr, int* __restrict__ rowptr,
                          float* __restrict__ dis, int n) {
  __shared__ int cnt[256], loff[256], cur[256], temp[BLK];
  int b = blockIdx.x, t = threadIdx.x;
  cnt[t] = 0; cur[t] = 0;
  __syncthreads();
  int s = base[b], e = base[b + 1];
  for (int i = s + t; i < e; i += BLK) atomicAdd(&cnt[binned[i] & 255], 1);
  __syncthreads();
  int v = cnt[t];
  temp[t] = v; __syncthreads();
  int inc = v;
  for (int off = 1; off < BLK; off <<= 1) {
    int u = (t >= off) ? temp[t - off] : 0; __syncthreads();
    inc += u; temp[t] = inc; __syncthreads();
  }
  loff[t] = inc - v;
  int node = b * 256 + t;
  if (node < n) {
    rowptr[node] = s + inc - v;
    dis[node] = rsqrtf((float)(v + 1));   // +1 self-loop
  }
  __syncthreads();
  for (int i = s + t; i < e; i += BLK) {
    int rec = binned[i];
    int L = rec & 255;
    int p = atomicAdd(&cur[L], 1);
    csr[s + loff[L] + p] = rec >> 8;
  }
}

// gather, wave-per-node: 64 lanes = 32 edges x 2 float4-halves of the y row
__global__ void k_gather(const int* __restrict__ rowptr, const int* __restrict__ csr,
                         const float* __restrict__ y, float* __restrict__ acc, int n) {
  int wid = (int)(((long long)blockIdx.x * BLK + threadIdx.x) >> 6);
  if (wid >= n) return;
  int lane = threadIdx.x & 63;
  int e = lane & 31, fq = lane >> 5;     // edge slot, feature quad
  int start = rowptr[wid], end = rowptr[wid + 1];
  float4 s = make_float4(0.f, 0.f, 0.f, 0.f);
  int k = start + e;
  int sidx = (k < end) ? csr[k] : -1;
  for (int k0 = start; k0 < end; k0 += 32) {
    int nk = k0 + 32 + e;
    int nsidx = (nk < end) ? csr[nk] : -1;   // prefetch next 32 sources
    if (sidx >= 0) {
      const float4 v = *(const float4*)(y + (size_t)sidx * 8 + fq * 4);
      s.x += v.x; s.y += v.y; s.z += v.z; s.w += v.w;
    }
    sidx = nsidx;
  }
  #pragma unroll
  for (int m = 1; m <= 16; m <<= 1) {
    s.x += __shfl_xor(s.x, m);
    s.y += __shfl_xor(s.y, m);
    s.z += __shfl_xor(s.z, m);
    s.w += __shfl_xor(s.w, m);
  }
  if (e == 0) *(float4*)(acc + (size_t)wid * 8 + fq * 4) = s;
}

// ================= tier-2 fallback (R5 proven) =================

__global__ void k_degdis(const int* __restrict__ base, const int* __restrict__ binned,
                         float* __restrict__ dis, int n) {
  __shared__ int deg[256];
  int b = blockIdx.x, t = threadIdx.x;
  deg[t] = 1;
  __syncthreads();
  int s = base[b], e = base[b + 1];
  for (int i = s + t; i < e; i += BLK) atomicAdd(&deg[binned[i] & 255], 1);
  __syncthreads();
  int node = b * 256 + t;
  if (node < n) dis[node] = rsqrtf((float)deg[t]);
}

__global__ void k_acc(const int* __restrict__ base, const int* __restrict__ binned,
                      const float* __restrict__ y, float* __restrict__ acc, int n) {
  __shared__ float fa[2048];
  int b = blockIdx.x, t = threadIdx.x;
  for (int i = t; i < 2048; i += BLK) fa[i] = 0.f;
  __syncthreads();
  int s = base[b], e = base[b + 1];
  int j = t & 7;
  for (int i = s + (t >> 3); i < e; i += 32) {
    int rec = binned[i];
    atomicAdd(&fa[(rec & 255) * 8 + j], y[(size_t)(rec >> 8) * 8 + j]);
  }
  __syncthreads();
  int node0 = b * 256;
  int lim = (n - node0 < 256 ? n - node0 : 256) * 8;
  for (int i = t; i < lim; i += BLK) acc[(size_t)node0 * 8 + i] = fa[i];
}

// ================= dense stages =================

__global__ void k_y1n(const float* __restrict__ x, const float* __restrict__ W1,
                      const float* __restrict__ dis, float* __restrict__ y, int n) {
  __shared__ float sW[128];
  if (threadIdx.x < 128) sW[threadIdx.x] = W1[threadIdx.x];
  __syncthreads();
  int i = blockIdx.x * BLK + threadIdx.x;
  if (i >= n) return;
  const float4* xp = (const float4*)(x + (size_t)i * 16);
  float4 a = xp[0], bb = xp[1], cc = xp[2], d4 = xp[3];
  float xv[16] = {a.x,a.y,a.z,a.w, bb.x,bb.y,bb.z,bb.w,
                  cc.x,cc.y,cc.z,cc.w, d4.x,d4.y,d4.z,d4.w};
  float ds = dis[i];
  float o[8];
  #pragma unroll
  for (int jj = 0; jj < 8; ++jj) {
    float s = 0.f;
    #pragma unroll
    for (int k = 0; k < 16; ++k) s = fmaf(xv[k], sW[k*8 + jj], s);
    o[jj] = ds * s;
  }
  float4* yp = (float4*)(y + (size_t)i * 8);
  yp[0] = make_float4(o[0], o[1], o[2], o[3]);
  yp[1] = make_float4(o[4], o[5], o[6], o[7]);
}

__global__ void k_mid(const float* __restrict__ dis, float* __restrict__ y,
                      float* __restrict__ acc, const float* __restrict__ W2,
                      const float* __restrict__ b1, int n, int zero_acc) {
  __shared__ float sW[64];
  __shared__ float sb[8];
  if (threadIdx.x < 64) sW[threadIdx.x] = W2[threadIdx.x];
  if (threadIdx.x < 8)  sb[threadIdx.x] = b1[threadIdx.x];
  __syncthreads();
  int i = blockIdx.x * BLK + threadIdx.x;
  if (i >= n) return;
  float d = dis[i];
  float4* yp = (float4*)(y + (size_t)i * 8);
  float4* ap = (float4*)(acc + (size_t)i * 8);
  float4 y0 = yp[0], y1v = yp[1], a0 = ap[0], a1 = ap[1];
  float yy[8] = {y0.x,y0.y,y0.z,y0.w, y1v.x,y1v.y,y1v.z,y1v.w};
  float aa[8] = {a0.x,a0.y,a0.z,a0.w, a1.x,a1.y,a1.z,a1.w};
  float hv[8];
  #pragma unroll
  for (int jj = 0; jj < 8; ++jj) hv[jj] = fmaxf(fmaf(d, yy[jj] + aa[jj], sb[jj]), 0.f);
  float o[8];
  #pragma unroll
  for (int jj = 0; jj < 8; ++jj) {
    float s = 0.f;
    #pragma unroll
    for (int k = 0; k < 8; ++k) s = fmaf(hv[k], sW[k*8 + jj], s);
    o[jj] = d * s;
  }
  yp[0] = make_float4(o[0], o[1], o[2], o[3]);
  yp[1] = make_float4(o[4], o[5], o[6], o[7]);
  if (zero_acc) {
    ap[0] = make_float4(0.f, 0.f, 0.f, 0.f);
    ap[1] = make_float4(0.f, 0.f, 0.f, 0.f);
  }
}

__global__ void k_final(const float* __restrict__ dis, const float* __restrict__ y,
                        const float* __restrict__ acc, const float* __restrict__ b2,
                        const float* __restrict__ Wl, const int* __restrict__ batch,
                        float* __restrict__ zacc, int n) {
  __shared__ float sb[8], sw[8];
  if (threadIdx.x < 8) { sb[threadIdx.x] = b2[threadIdx.x]; sw[threadIdx.x] = Wl[threadIdx.x]; }
  __syncthreads();
  int i = blockIdx.x * BLK + threadIdx.x;
  float s = 0.f;
  int g = -1;
  if (i < n) {
    float d = dis[i];
    const float4* yp = (const float4*)(y + (size_t)i * 8);
    const float4* ap = (const float4*)(acc + (size_t)i * 8);
    float4 y0 = yp[0], y1v = yp[1], a0 = ap[0], a1 = ap[1];
    float yy[8] = {y0.x,y0.y,y0.z,y0.w, y1v.x,y1v.y,y1v.z,y1v.w};
    float aa[8] = {a0.x,a0.y,a0.z,a0.w, a1.x,a1.y,a1.z,a1.w};
    #pragma unroll
    for (int jj = 0; jj < 8; ++jj) {
      float h = fmaxf(fmaf(d, yy[jj] + aa[jj], sb[jj]), 0.f);
      s = fmaf(h, sw[jj], s);
    }
    g = batch[i];
  }
  int g0 = __shfl(g, 0);
  bool uni = __all(g == g0);
  if (uni) {
    #pragma unroll
    for (int off = 32; off > 0; off >>= 1) s += __shfl_down(s, off);
    if ((threadIdx.x & 63) == 0 && g0 >= 0) unsafeAtomicAdd(&zacc[g0], s);
  } else if (i < n) {
    unsafeAtomicAdd(&zacc[g], s);
  }
}

__global__ void k_out(const float* __restrict__ zacc, const float* __restrict__ bl,
                      float* __restrict__ out, int ng) {
  int i = blockIdx.x * BLK + threadIdx.x;
  if (i < ng) {
    float z = zacc[i] + bl[0];
    float r;
    if (z >= 0.f) { r = 1.f / (1.f + expf(-z)); }
    else          { float e = expf(z); r = e / (1.f + e); }
    out[i] = r;
  }
}

// ================= tier-3 fallback (R2 proven) =================

__global__ void k_init(int* __restrict__ deg, float* __restrict__ acc,
                       float* __restrict__ zacc, int n, int accn, int ng) {
  int jj = blockIdx.x * BLK + threadIdx.x;
  if (jj < accn) acc[jj] = 0.f;
  if (jj < n) deg[jj] = 1;
  if (jj < ng) zacc[jj] = 0.f;
}

__global__ void k_deg(const int* __restrict__ dst, int* __restrict__ deg, int E) {
  int i = blockIdx.x * BLK + threadIdx.x;
  if (i < E) atomicAdd(&deg[dst[i]], 1);
}

__global__ void k_y1(const float* __restrict__ x, const float* __restrict__ W1,
                     int* __restrict__ degdis, float* __restrict__ y, int n) {
  __shared__ float sW[128];
  if (threadIdx.x < 128) sW[threadIdx.x] = W1[threadIdx.x];
  __syncthreads();
  int i = blockIdx.x * BLK + threadIdx.x;
  if (i >= n) return;
  const float4* xp = (const float4*)(x + (size_t)i * 16);
  float4 a = xp[0], bb = xp[1], cc = xp[2], d4 = xp[3];
  float xv[16] = {a.x,a.y,a.z,a.w, bb.x,bb.y,bb.z,bb.w,
                  cc.x,cc.y,cc.z,cc.w, d4.x,d4.y,d4.z,d4.w};
  float ds = rsqrtf((float)degdis[i]);
  float o[8];
  #pragma unroll
  for (int jj = 0; jj < 8; ++jj) {
    float s = 0.f;
    #pragma unroll
    for (int k = 0; k < 16; ++k) s = fmaf(xv[k], sW[k*8 + jj], s);
    o[jj] = ds * s;
  }
  ((float*)degdis)[i] = ds;
  float4* yp = (float4*)(y + (size_t)i * 8);
  yp[0] = make_float4(o[0], o[1], o[2], o[3]);
  yp[1] = make_float4(o[4], o[5], o[6], o[7]);
}

__global__ void k_scatter(const int* __restrict__ src, const int* __restrict__ dst,
                          const float* __restrict__ y, float* __restrict__ acc,
                          long long total) {
  long long t = (long long)blockIdx.x * BLK + threadIdx.x;
  if (t >= total) return;
  int e = (int)(t >> 3);
  int h = (int)(t & 7);
  int s = src[e], d = dst[e];
  unsafeAtomicAdd(&acc[(size_t)d * 8 + h], y[(size_t)s * 8 + h]);
}

// ================= host =================

static inline size_t alignup(size_t v) { return (v + 255) & ~(size_t)255; }

extern "C" void kernel_launch(void* const* d_in, const int* in_sizes, int n_in,
                              void* d_out, int out_size, void* d_ws, size_t ws_size,
                              hipStream_t stream) {
  const float* x   = (const float*)d_in[0];
  const int*   ei  = (const int*)  d_in[1];
  const int*   bat = (const int*)  d_in[2];
  const float* W1  = (const float*)d_in[3];
  const float* b1  = (const float*)d_in[4];
  const float* W2  = (const float*)d_in[5];
  const float* b2  = (const float*)d_in[6];
  const float* Wl  = (const float*)d_in[7];
  const float* bl  = (const float*)d_in[8];
  float* out = (float*)d_out;

  int n  = in_sizes[0] / 16;   // 250000
  int E  = in_sizes[1] / 2;    // 8000000
  int ng = out_size;           // 512

  const int* src = ei;
  const int* dst = ei + E;

  int nb = (n + 255) >> 8;     // 977

  char* wsb = (char*)d_ws;
  size_t offY  = alignup((size_t)n * 4);                  // dis
  size_t offA  = offY + alignup((size_t)n * 8 * 4);       // y
  size_t offZ  = offA + alignup((size_t)n * 8 * 4);       // acc
  size_t offH  = offZ + alignup((size_t)ng * 4);          // zacc
  size_t offB  = offH + alignup((size_t)NBMAX * 4);       // ghist
  size_t offCu = offB + alignup((size_t)(NBMAX + 1) * 4); // base
  size_t offBn = offCu + alignup((size_t)NBMAX * 4);      // cursor
  size_t offRp = offBn + alignup((size_t)E * 4);          // binned
  size_t offCs = offRp + alignup(((size_t)n + 1) * 4);    // rowptr
  size_t need1 = offCs + alignup((size_t)E * 4);          // csr
  size_t need2 = offRp;                                   // tier-2: through binned

  float* dis    = (float*)wsb;
  int*   deg    = (int*)wsb;
  float* y      = (float*)(wsb + offY);
  float* acc    = (float*)(wsb + offA);
  float* zacc   = (float*)(wsb + offZ);
  int*   ghist  = (int*)(wsb + offH);
  int*   base   = (int*)(wsb + offB);
  int*   cursor = (int*)(wsb + offCu);
  int*   binned = (int*)(wsb + offBn);
  int*   rowptr = (int*)(wsb + offRp);
  int*   csr    = (int*)(wsb + offCs);

  int gN = (n + BLK - 1) / BLK;
  int gG = (ng + BLK - 1) / BLK;
  int gW = (int)(((long long)n * 64 + BLK - 1) / BLK);   // wave-per-node gather

  bool ok_bin = (nb <= NBMAX) && (n < (1 << 23));
  bool tier1 = ok_bin && (ws_size >= need1);
  bool tier2 = ok_bin && (ws_size >= need2);

  if (tier1 || tier2) {
    int histChunk = 4096;
    int gHist = (int)(((long long)E + histChunk - 1) / histChunk);
    int gBin  = (int)(((long long)E + CH - 1) / CH);
    int gI0   = (NBMAX > ng ? NBMAX : ng) / BLK + 1;
    k_init0 <<<gI0, BLK, 0, stream>>>(ghist, zacc, rowptr, NBMAX, ng, n, E, tier1 ? 1 : 0);
    k_hist  <<<gHist, BLK, 0, stream>>>(dst, ghist, E, nb, histChunk);
    k_scan  <<<1, BLK, 0, stream>>>(ghist, base, cursor, nb, E);
    k_bin   <<<gBin, BLK, 0, stream>>>(src, dst, cursor, binned, E, nb);
    if (tier1) {
      k_sortdis<<<nb, BLK, 0, stream>>>(base, binned, csr, rowptr, dis, n);
      k_y1n   <<<gN, BLK, 0, stream>>>(x, W1, dis, y, n);
      k_gather<<<gW, BLK, 0, stream>>>(rowptr, csr, y, acc, n);
      k_mid   <<<gN, BLK, 0, stream>>>(dis, y, acc, W2, b1, n, 0);
      k_gather<<<gW, BLK, 0, stream>>>(rowptr, csr, y, acc, n);
    } else {
      k_degdis<<<nb, BLK, 0, stream>>>(base, binned, dis, n);
      k_y1n   <<<gN, BLK, 0, stream>>>(x, W1, dis, y, n);
      k_acc   <<<nb, BLK, 0, stream>>>(base, binned, y, acc, n);
      k_mid   <<<gN, BLK, 0, stream>>>(dis, y, acc, W2, b1, n, 0);
      k_acc   <<<nb, BLK, 0, stream>>>(base, binned, y, acc, n);
    }
    k_final <<<gN, BLK, 0, stream>>>(dis, y, acc, b2, Wl, bat, zacc, n);
  } else {
    int accn = n * 8;
    long long tot = (long long)E * 8;
    int gInit = (accn + BLK - 1) / BLK;
    int gE    = (E + BLK - 1) / BLK;
    int gS    = (int)((tot + BLK - 1) / BLK);
    k_init   <<<gInit, BLK, 0, stream>>>(deg, acc, zacc, n, accn, ng);
    k_deg    <<<gE, BLK, 0, stream>>>(dst, deg, E);
    k_y1     <<<gN, BLK, 0, stream>>>(x, W1, deg, y, n);
    k_scatter<<<gS, BLK, 0, stream>>>(src, dst, y, acc, tot);
    k_mid    <<<gN, BLK, 0, stream>>>(dis, y, acc, W2, b1, n, 1);
    k_scatter<<<gS, BLK, 0, stream>>>(src, dst, y, acc, tot);
    k_final  <<<gN, BLK, 0, stream>>>(dis, y, acc, b2, Wl, bat, zacc, n);
  }
  k_out<<<gG, BLK, 0, stream>>>(zacc, bl, out, ng);
}